// Round 1
// baseline (12223.883 us; speedup 1.0000x reference)
//
#include <hip/hip_runtime.h>

typedef __bf16 bf16;
typedef __bf16 v8bf __attribute__((ext_vector_type(8)));
typedef __bf16 v4bf __attribute__((ext_vector_type(4)));
typedef float  v4f  __attribute__((ext_vector_type(4)));

// B=128, T=256, D=1024, H=1024, V=1024, S=128 (all K dims used are 1024)

static __device__ __forceinline__ float fast_tanh(float x) {
  x = fminf(fmaxf(x, -10.f), 10.f);
  float e = __expf(2.f * x);
  return (e - 1.f) * __builtin_amdgcn_rcpf(e + 1.f);
}
static __device__ __forceinline__ float fast_sigmoid(float x) {
  return __builtin_amdgcn_rcpf(1.f + __expf(-x));
}

// ---------------------------------------------------------------------------
// Generic bf16 GEMM: C[M,N] = A[M,K] @ B[N,K]^T (+bias[n]) (opt tanh)
// Tile 64x64, BK=64, 256 threads (4 waves, 2x2 of 32x32), mfma 16x16x32 bf16.
// A,B staged via global_load_lds width=16 (linear LDS layout, wave-uniform+lane*16).
// ---------------------------------------------------------------------------
template<bool BIAS, bool TANH, bool SF32, bool SB16>
__global__ __launch_bounds__(256)
void kGemm(const bf16* __restrict__ A, int lda,
           const bf16* __restrict__ Bm, int ldb,
           const float* __restrict__ bias,
           float* __restrict__ Cf, bf16* __restrict__ Cb, int ldc, int K)
{
  __shared__ bf16 As[64 * 64];
  __shared__ bf16 Bs[64 * 64];
  const int tid  = threadIdx.x;
  const int lane = tid & 63, w = tid >> 6;
  const int wr = w >> 1, wc = w & 1;
  const int n0 = blockIdx.x * 64, m0 = blockIdx.y * 64;
  const int r0 = tid >> 3, c0 = (tid & 7) * 8;   // staging: row, col(el) within tile

  v4f acc[2][2] = {};

  const bf16* ap = A  + (size_t)(m0 + r0) * lda + c0;
  const bf16* bp = Bm + (size_t)(n0 + r0) * ldb + c0;

  for (int k0 = 0; k0 < K; k0 += 64) {
    __builtin_amdgcn_global_load_lds((const __attribute__((address_space(1))) void*)(ap + k0),
                                     (__attribute__((address_space(3))) void*)(As + tid * 8), 16, 0, 0);
    __builtin_amdgcn_global_load_lds((const __attribute__((address_space(1))) void*)(ap + (size_t)32 * lda + k0),
                                     (__attribute__((address_space(3))) void*)(As + 2048 + tid * 8), 16, 0, 0);
    __builtin_amdgcn_global_load_lds((const __attribute__((address_space(1))) void*)(bp + k0),
                                     (__attribute__((address_space(3))) void*)(Bs + tid * 8), 16, 0, 0);
    __builtin_amdgcn_global_load_lds((const __attribute__((address_space(1))) void*)(bp + (size_t)32 * ldb + k0),
                                     (__attribute__((address_space(3))) void*)(Bs + 2048 + tid * 8), 16, 0, 0);
    __syncthreads();   // compiler inserts s_waitcnt vmcnt(0) before barrier
#pragma unroll
    for (int ks = 0; ks < 2; ks++) {
      const int kk = ks * 32 + (lane >> 4) * 8;
      v8bf a0 = *(const v8bf*)(As + (wr * 32 +      (lane & 15)) * 64 + kk);
      v8bf a1 = *(const v8bf*)(As + (wr * 32 + 16 + (lane & 15)) * 64 + kk);
      v8bf b0 = *(const v8bf*)(Bs + (wc * 32 +      (lane & 15)) * 64 + kk);
      v8bf b1 = *(const v8bf*)(Bs + (wc * 32 + 16 + (lane & 15)) * 64 + kk);
      acc[0][0] = __builtin_amdgcn_mfma_f32_16x16x32_bf16(a0, b0, acc[0][0], 0, 0, 0);
      acc[0][1] = __builtin_amdgcn_mfma_f32_16x16x32_bf16(a0, b1, acc[0][1], 0, 0, 0);
      acc[1][0] = __builtin_amdgcn_mfma_f32_16x16x32_bf16(a1, b0, acc[1][0], 0, 0, 0);
      acc[1][1] = __builtin_amdgcn_mfma_f32_16x16x32_bf16(a1, b1, acc[1][1], 0, 0, 0);
    }
    __syncthreads();
  }

  // C/D layout (m89-verified): col = lane&15 (n), row = (lane>>4)*4 + i (m)
  const int mBase = m0 + wr * 32 + (lane >> 4) * 4;
  const int nBase = n0 + wc * 32 + (lane & 15);
#pragma unroll
  for (int mf = 0; mf < 2; mf++)
#pragma unroll
    for (int nf = 0; nf < 2; nf++) {
      const int n = nBase + nf * 16;
      float bv = BIAS ? bias[n] : 0.f;
#pragma unroll
      for (int i = 0; i < 4; i++) {
        const int m = mBase + mf * 16 + i;
        float v = acc[mf][nf][i] + bv;
        if (TANH) v = fast_tanh(v);
        if (SF32) Cf[(size_t)m * ldc + n] = v;
        if (SB16) Cb[(size_t)m * ldc + n] = (bf16)v;
      }
    }
}

// ---------------------------------------------------------------------------
// Attention: one wg (1024 thr) per batch element b.
// scores[t] = sum_h w_a[h] * tanh(wh+sa)  via tanh-addition identity with
// precomputed tw=tanh(wh) (bf16); softmax (no max-sub: |score|<=16); context.
// ---------------------------------------------------------------------------
__global__ __launch_bounds__(1024)
void kAttn(const float* __restrict__ sagh,   // 128x4096 f32, cols 0..1023 = sa (pre-tanh)
           const bf16* __restrict__ twb,     // tanh(wh) (B,T,H) bf16
           const bf16* __restrict__ hb,      // (B,T,D) bf16
           const float* __restrict__ w_a,    // (H)
           bf16* __restrict__ c_b16)         // (B,D)
{
  __shared__ float ts[1024], wa[1024], esh[256];
  __shared__ float rden_s;
  const int b = blockIdx.x;
  const int tid = threadIdx.x, lane = tid & 63, w = tid >> 6;

  // ts = tanh(sa); clamp away from +-1 so identity denominator never hits 0
  float t0 = fast_tanh(sagh[(size_t)b * 4096 + tid]);
  ts[tid] = fminf(fmaxf(t0, -0.99999994f), 0.99999994f);
  wa[tid] = w_a[tid];
  __syncthreads();

  float tj[16], wj[16];
#pragma unroll
  for (int j = 0; j < 16; j++) { tj[j] = ts[lane + 64 * j]; wj[j] = wa[lane + 64 * j]; }

  for (int t = w; t < 256; t += 16) {   // each wave handles 16 t's
    const bf16* tw = twb + ((size_t)b * 256 + t) * 1024;
    float acc = 0.f;
#pragma unroll
    for (int j = 0; j < 16; j++) {
      float twv = (float)tw[lane + 64 * j];
      float num = twv + tj[j];
      float den = 1.f + twv * tj[j];
      acc += wj[j] * num * __builtin_amdgcn_rcpf(den);
    }
#pragma unroll
    for (int off = 32; off; off >>= 1) acc += __shfl_down(acc, off, 64);
    if (lane == 0) esh[t] = __expf(acc);
  }
  __syncthreads();
  if (w == 0) {
    float p = esh[lane] + esh[lane + 64] + esh[lane + 128] + esh[lane + 192];
#pragma unroll
    for (int off = 32; off; off >>= 1) p += __shfl_down(p, off, 64);
    if (lane == 0) rden_s = 1.f / p;
  }
  __syncthreads();
  const float rden = rden_s;
  // context: thread d = tid
  const bf16* hrow = hb + (size_t)b * 256 * 1024 + tid;
  float cacc = 0.f;
#pragma unroll 8
  for (int t = 0; t < 256; t++) cacc += esh[t] * (float)hrow[(size_t)t * 1024];
  c_b16[(size_t)b * 1024 + tid] = (bf16)(cacc * rden);
}

// GRU pointwise: s_new = (1-z)*n + z*s
__global__ __launch_bounds__(256)
void kGru(const float* __restrict__ gcp, const float* __restrict__ ygp,
          const float* __restrict__ sagh, float* __restrict__ s_f32,
          bf16* __restrict__ s_b16)
{
  const int idx = blockIdx.x * 256 + threadIdx.x;   // 0..131071
  const int b = idx >> 10, j = idx & 1023;
  const size_t o = (size_t)b * 4096;
  float ir  = gcp[o + j]        + ygp[o + j];
  float iz  = gcp[o + 1024 + j] + ygp[o + 1024 + j];
  float in_ = gcp[o + 2048 + j] + ygp[o + 2048 + j];
  float hr  = sagh[o + 1024 + j];
  float hz  = sagh[o + 2048 + j];
  float hn  = sagh[o + 3072 + j];
  float r = fast_sigmoid(ir + hr);
  float z = fast_sigmoid(iz + hz);
  float n = fast_tanh(in_ + r * hn);
  float s = s_f32[idx];
  float sn = (1.f - z) * n + z * s;
  s_f32[idx] = sn;
  s_b16[idx] = (bf16)sn;
}

// RNN output: pre = pres + prec + prey(+biases); y = softmax(tanh(pre)); write out + y_b16
__global__ __launch_bounds__(256)
void kOut(const float* __restrict__ pres, const float* __restrict__ gcp,
          const float* __restrict__ ygp, float* __restrict__ out,
          bf16* __restrict__ y_b16, int step)
{
  __shared__ float wsum[4];
  __shared__ float rden_s;
  const int b = blockIdx.x, tid = threadIdx.x, lane = tid & 63, w = tid >> 6;
  float e[4];
  float p = 0.f;
#pragma unroll
  for (int j = 0; j < 4; j++) {
    const int v = tid + 256 * j;
    float pre = pres[(size_t)b * 1024 + v] + gcp[(size_t)b * 4096 + 3072 + v]
              + ygp[(size_t)b * 4096 + 3072 + v];
    e[j] = __expf(fast_tanh(pre));
    p += e[j];
  }
#pragma unroll
  for (int off = 32; off; off >>= 1) p += __shfl_down(p, off, 64);
  if (lane == 0) wsum[w] = p;
  __syncthreads();
  if (tid == 0) rden_s = 1.f / (wsum[0] + wsum[1] + wsum[2] + wsum[3]);
  __syncthreads();
  const float rden = rden_s;
#pragma unroll
  for (int j = 0; j < 4; j++) {
    const int v = tid + 256 * j;
    float y = e[j] * rden;
    out[((size_t)b * 128 + step) * 1024 + v] = y;
    y_b16[(size_t)b * 1024 + v] = (bf16)y;
  }
}

// Setup: f32 -> bf16 casts (vectorized x4)
__global__ void kCast4(const float* __restrict__ src, bf16* __restrict__ dst, int n4) {
  int i = blockIdx.x * 256 + threadIdx.x;
  if (i < n4) {
    v4f v = ((const v4f*)src)[i];
    ((v4bf*)dst)[i] = __builtin_convertvector(v, v4bf);
  }
}
// strided rows of 1024 cols from src (row stride src_ld els; col offset baked into src ptr)
__global__ void kCastStrided(const float* __restrict__ src, int src_ld, bf16* __restrict__ dst, int n4) {
  int i = blockIdx.x * 256 + threadIdx.x;
  if (i < n4) {
    int r = i >> 8, c4 = i & 255;
    v4f v = *(const v4f*)(src + (size_t)r * src_ld + c4 * 4);
    ((v4bf*)dst)[i] = __builtin_convertvector(v, v4bf);
  }
}
// bias concats + zero y0
__global__ void kPrep(const float* b_s_a, const float* gru_b_hh,
                      const float* gru_b_ih, const float* rnn_b_ih, const float* rnn_b_hh,
                      float* b_cat1, float* b_cat2, bf16* y_b16) {
  int i = blockIdx.x * 256 + threadIdx.x;
  if (i < 4096) {
    b_cat1[i] = (i < 1024) ? b_s_a[i] : gru_b_hh[i - 1024];
  } else if (i < 8192) {
    int j = i - 4096;
    b_cat2[j] = (j < 3072) ? gru_b_ih[j] : (rnn_b_ih[j - 3072] + rnn_b_hh[j - 3072]);
  } else {
    int j = i - 8192;
    if (j < 131072) y_b16[j] = (bf16)0.f;
  }
}

extern "C" void kernel_launch(void* const* d_in, const int* in_sizes, int n_in,
                              void* d_out, int out_size, void* d_ws, size_t ws_size,
                              hipStream_t stream) {
  const float* h        = (const float*)d_in[0];
  const float* w_h_a    = (const float*)d_in[1];
  const float* w_s_a    = (const float*)d_in[2];
  const float* b_s_a    = (const float*)d_in[3];
  const float* w_a      = (const float*)d_in[4];
  const float* w_init_s = (const float*)d_in[5];
  const float* b_init_s = (const float*)d_in[6];
  const float* gru_w_ih = (const float*)d_in[7];
  const float* gru_w_hh = (const float*)d_in[8];
  const float* gru_b_ih = (const float*)d_in[9];
  const float* gru_b_hh = (const float*)d_in[10];
  const float* rnn_w_ih = (const float*)d_in[11];
  const float* rnn_w_hh = (const float*)d_in[12];
  const float* rnn_b_ih = (const float*)d_in[13];
  const float* rnn_b_hh = (const float*)d_in[14];
  float* out = (float*)d_out;

  char* p = (char*)d_ws;
  auto alloc = [&](size_t bytes) { char* r = p; p += (bytes + 255) & ~(size_t)255; return r; };
  bf16* hb     = (bf16*)alloc(33554432ull * 2);           // bf16(h)           64 MiB
  bf16* twb    = (bf16*)alloc(33554432ull * 2);           // tanh(h@w_h_a.T)   64 MiB
  bf16* wcat1  = (bf16*)alloc(4096ull * 1024 * 2);        // [w_s_a; gru_w_hh]
  bf16* wcat2  = (bf16*)alloc(4096ull * 1024 * 2);        // [gru_w_ih[:,1024:]; rnn_w_hh]
  bf16* wcat3  = (bf16*)alloc(4096ull * 1024 * 2);        // [gru_w_ih[:,:1024]; rnn_w_ih[:,:1024]]
  bf16* wcat4  = (bf16*)alloc(1024ull * 1024 * 2);        // rnn_w_ih[:,1024:]
  bf16* wbha   = (bf16*)alloc(1024ull * 1024 * 2);        // w_h_a
  bf16* wbini  = (bf16*)alloc(1024ull * 1024 * 2);        // w_init_s
  float* bcat1 = (float*)alloc(4096 * 4);
  float* bcat2 = (float*)alloc(4096 * 4);
  float* sagh  = (float*)alloc(128ull * 4096 * 4);        // [sa | gh]
  float* ygp   = (float*)alloc(128ull * 4096 * 4);        // [giy | prey] (+biases)
  float* gcp   = (float*)alloc(128ull * 4096 * 4);        // [gic | prec]
  float* presb = (float*)alloc(128ull * 1024 * 4);
  float* s_f32 = (float*)alloc(128ull * 1024 * 4);
  bf16* s_b16  = (bf16*)alloc(128ull * 1024 * 2);
  bf16* y_b16  = (bf16*)alloc(128ull * 1024 * 2);
  bf16* c_b16  = (bf16*)alloc(128ull * 1024 * 2);
  (void)ws_size; (void)in_sizes; (void)n_in; (void)out_size;

  // ---- one-time setup (rebuilt every call; ws is re-poisoned by harness) ----
  kCast4<<<dim3(32768), 256, 0, stream>>>(h, hb, 8388608);
  kCast4<<<dim3(1024), 256, 0, stream>>>(w_h_a, wbha, 262144);
  kCast4<<<dim3(1024), 256, 0, stream>>>(w_init_s, wbini, 262144);
  kCast4<<<dim3(1024), 256, 0, stream>>>(w_s_a, wcat1, 262144);
  kCast4<<<dim3(3072), 256, 0, stream>>>(gru_w_hh, wcat1 + 1024 * 1024, 786432);
  kCast4<<<dim3(1024), 256, 0, stream>>>(rnn_w_hh, wcat2 + 3072 * 1024, 262144);
  kCastStrided<<<dim3(3072), 256, 0, stream>>>(gru_w_ih + 1024, 2048, wcat2, 786432);
  kCastStrided<<<dim3(3072), 256, 0, stream>>>(gru_w_ih, 2048, wcat3, 786432);
  kCastStrided<<<dim3(1024), 256, 0, stream>>>(rnn_w_ih, 2048, wcat3 + 3072 * 1024, 262144);
  kCastStrided<<<dim3(1024), 256, 0, stream>>>(rnn_w_ih + 1024, 2048, wcat4, 262144);
  kPrep<<<dim3(544), 256, 0, stream>>>(b_s_a, gru_b_hh, gru_b_ih, rnn_b_ih, rnn_b_hh, bcat1, bcat2, y_b16);
  // tw = tanh(h @ w_h_a.T) -> bf16 (M=32768, N=1024, K=1024)
  kGemm<false, true, false, true><<<dim3(16, 512), 256, 0, stream>>>(hb, 1024, wbha, 1024, nullptr, nullptr, twb, 1024, 1024);
  // s0 = tanh(h[:,0,:] @ w_init_s.T + b_init_s)  (A rows stride T*D)
  kGemm<true, true, true, true><<<dim3(16, 2), 256, 0, stream>>>(hb, 262144, wbini, 1024, b_init_s, s_f32, s_b16, 1024, 1024);

  // ---- 128 sequential decode steps ----
  for (int step = 0; step < 128; step++) {
    // [sa | gh] = s @ [w_s_a; gru_w_hh]^T + [b_s_a; gru_b_hh]
    kGemm<true, false, true, false><<<dim3(64, 2), 256, 0, stream>>>(s_b16, 1024, wcat1, 1024, bcat1, sagh, nullptr, 4096, 1024);
    // [giy | prey] = y @ [gru_w_ih_y; rnn_w_hh]^T + [gru_b_ih; rnn_b_ih+rnn_b_hh]
    kGemm<true, false, true, false><<<dim3(64, 2), 256, 0, stream>>>(y_b16, 1024, wcat2, 1024, bcat2, ygp, nullptr, 4096, 1024);
    // attention: scores -> softmax -> context (per-b local)
    kAttn<<<dim3(128), 1024, 0, stream>>>(sagh, twb, hb, w_a, c_b16);
    // [gic | prec] = c @ [gru_w_ih_c; rnn_w_ih_c]^T
    kGemm<false, false, true, false><<<dim3(64, 2), 256, 0, stream>>>(c_b16, 1024, wcat3, 1024, nullptr, gcp, nullptr, 4096, 1024);
    // GRU pointwise -> s_new
    kGru<<<dim3(512), 256, 0, stream>>>(gcp, ygp, sagh, s_f32, s_b16);
    // pres = s_new @ rnn_w_ih_s^T
    kGemm<false, false, true, false><<<dim3(16, 2), 256, 0, stream>>>(s_b16, 1024, wcat4, 1024, nullptr, presb, nullptr, 1024, 1024);
    // pre -> tanh -> softmax -> out[:, step, :], y_b16
    kOut<<<dim3(128), 256, 0, stream>>>(presb, gcp, ygp, out, y_b16, step);
  }
}

// Round 3
// 8711.413 us; speedup vs baseline: 1.4032x; 1.4032x over previous
//
#include <hip/hip_runtime.h>

typedef __bf16 bf16;
typedef __bf16 v8bf __attribute__((ext_vector_type(8)));
typedef __bf16 v4bf __attribute__((ext_vector_type(4)));
typedef float  v4f  __attribute__((ext_vector_type(4)));

// B=128, T=256, D=H=V=1024, S=128. All GEMM K dims = 1024.

static __device__ __forceinline__ float fast_tanh(float x) {
  x = fminf(fmaxf(x, -10.f), 10.f);
  float e = __expf(2.f * x);
  return (e - 1.f) * __builtin_amdgcn_rcpf(e + 1.f);
}
static __device__ __forceinline__ float fast_sigmoid(float x) {
  return __builtin_amdgcn_rcpf(1.f + __expf(-x));
}

// ---------------------------------------------------------------------------
// MFMA-fragment packing: element (r,k) of X[R][1024] lives at
//   off = (((r>>4)*32 + (k>>5))*64 + ((k>>3)&3)*16 + (r&15))*8 + (k&7)
// so a GEMM wave loads lane-linear 16B chunks (global_load_dwordx4, no LDS).
// Derived from the round-1 HW-verified mfma_f32_16x16x32_bf16 A/B layout:
//   r = rb*16 + (lane&15), k = ks*32 + (lane>>4)*8 + e.
// ---------------------------------------------------------------------------
static __device__ __forceinline__ size_t packOff(int r, int k) {
  return ((size_t)((r >> 4) * 32 + (k >> 5)) * 64 + ((k >> 3) & 3) * 16 + (r & 15)) * 8 + (k & 7);
}

// No-LDS GEMM tile core: 64x64 tile, 256 thr (4 waves, 2x2 of 32x32), both
// operands fragment-packed in global (L2/L3-resident). NKS = # 32-wide k-steps.
template<int NKS>
static __device__ __forceinline__ void gemmTile(const bf16* __restrict__ Ap,
                                                const bf16* __restrict__ Bp,
                                                int m0, int n0, int ks0,
                                                v4f acc[2][2]) {
  const int lane = threadIdx.x & 63;
  const int w = threadIdx.x >> 6;
  const int wr = w >> 1, wc = w & 1;
  const bf16* a0p = Ap + (((size_t)((m0 >> 4) + wr * 2) * 32 + ks0) * 64 + lane) * 8;
  const bf16* b0p = Bp + (((size_t)((n0 >> 4) + wc * 2) * 32 + ks0) * 64 + lane) * 8;
#pragma unroll 8
  for (int ks = 0; ks < NKS; ks++) {
    v8bf a0 = *(const v8bf*)(a0p);
    v8bf a1 = *(const v8bf*)(a0p + 16384);   // next 16-row block: 32*64*8
    v8bf b0 = *(const v8bf*)(b0p);
    v8bf b1 = *(const v8bf*)(b0p + 16384);
    a0p += 512; b0p += 512;
    acc[0][0] = __builtin_amdgcn_mfma_f32_16x16x32_bf16(a0, b0, acc[0][0], 0, 0, 0);
    acc[0][1] = __builtin_amdgcn_mfma_f32_16x16x32_bf16(a0, b1, acc[0][1], 0, 0, 0);
    acc[1][0] = __builtin_amdgcn_mfma_f32_16x16x32_bf16(a1, b0, acc[1][0], 0, 0, 0);
    acc[1][1] = __builtin_amdgcn_mfma_f32_16x16x32_bf16(a1, b1, acc[1][1], 0, 0, 0);
  }
}

// C/D layout (round-1 HW-verified): col = lane&15, row = (lane>>4)*4 + i
static __device__ __forceinline__ void storeTileF32(float* __restrict__ C, int ldc,
                                                    int m0, int n0, v4f acc[2][2]) {
  const int lane = threadIdx.x & 63, w = threadIdx.x >> 6;
  const int wr = w >> 1, wc = w & 1;
  const int mB = m0 + wr * 32 + (lane >> 4) * 4;
  const int nB = n0 + wc * 32 + (lane & 15);
#pragma unroll
  for (int mf = 0; mf < 2; mf++)
#pragma unroll
    for (int nf = 0; nf < 2; nf++)
#pragma unroll
      for (int i = 0; i < 4; i++)
        C[(size_t)(mB + mf * 16 + i) * ldc + nB + nf * 16] = acc[mf][nf][i];
}

// ---------------------------------------------------------------------------
// Setup kernels
// ---------------------------------------------------------------------------
// f32 [r][k] (row stride ld) -> fragment-packed bf16. One thread = one 8-el frag.
__global__ __launch_bounds__(256) void kPack(const float* __restrict__ src, int ld,
                                             bf16* __restrict__ dst, int nTh) {
  int th = blockIdx.x * 256 + threadIdx.x;
  if (th >= nTh) return;
  int rb = th >> 11, ks = (th >> 6) & 31, l = th & 63;
  int r = rb * 16 + (l & 15);
  int k = ks * 32 + ((l >> 4) & 3) * 8;
  const float* s = src + (size_t)r * ld + k;
  v4f v0 = *(const v4f*)(s);
  v4f v1 = *(const v4f*)(s + 4);
  v8bf o;
#pragma unroll
  for (int e = 0; e < 4; e++) { o[e] = (bf16)v0[e]; o[4 + e] = (bf16)v1[e]; }
  *(v8bf*)(dst + (size_t)th * 8) = o;
}

// plain f32 -> bf16 linear cast (x4)
__global__ __launch_bounds__(256) void kCast4(const float* __restrict__ src,
                                              bf16* __restrict__ dst, int n4) {
  int i = blockIdx.x * 256 + threadIdx.x;
  if (i < n4) {
    v4f v = ((const v4f*)src)[i];
    ((v4bf*)dst)[i] = __builtin_convertvector(v, v4bf);
  }
}

// bias sum + zero y0 (packed order: zero is zero)
__global__ __launch_bounds__(256) void kPrep(const float* rnn_b_ih, const float* rnn_b_hh,
                                             float* bsum, bf16* y_b16p) {
  int th = blockIdx.x * 256 + threadIdx.x;
  if (th < 16384) {
    v8bf z = {};
    ((v8bf*)y_b16p)[th] = z;
  } else {
    int j = th - 16384;
    bsum[j] = rnn_b_ih[j] + rnn_b_hh[j];
  }
}

// tw = tanh(h @ w_h_a^T) -> bf16 linear (M=32768, N=1024)
__global__ __launch_bounds__(256) void kGemmTW(const bf16* __restrict__ Ap,
                                               const bf16* __restrict__ Bp,
                                               bf16* __restrict__ C) {
  const int nt = blockIdx.x & 15, mt = blockIdx.x >> 4;
  v4f acc[2][2] = {};
  gemmTile<32>(Ap, Bp, mt * 64, nt * 64, 0, acc);
  const int lane = threadIdx.x & 63, w = threadIdx.x >> 6;
  const int wr = w >> 1, wc = w & 1;
  const int mB = mt * 64 + wr * 32 + (lane >> 4) * 4;
  const int nB = nt * 64 + wc * 32 + (lane & 15);
#pragma unroll
  for (int mf = 0; mf < 2; mf++)
#pragma unroll
    for (int nf = 0; nf < 2; nf++)
#pragma unroll
      for (int i = 0; i < 4; i++)
        C[(size_t)(mB + mf * 16 + i) * 1024 + nB + nf * 16] = (bf16)fast_tanh(acc[mf][nf][i]);
}

// s0 = tanh(h0 @ w_init_s^T + b_init_s) -> packed f32 + packed bf16 (M=128)
__global__ __launch_bounds__(256) void kGemmS0(const bf16* __restrict__ Ap,
                                               const bf16* __restrict__ Bp,
                                               const float* __restrict__ bias,
                                               float* __restrict__ sF, bf16* __restrict__ sB) {
  const int nt = blockIdx.x & 15, mt = blockIdx.x >> 4;
  v4f acc[2][2] = {};
  gemmTile<32>(Ap, Bp, mt * 64, nt * 64, 0, acc);
  const int lane = threadIdx.x & 63, w = threadIdx.x >> 6;
  const int wr = w >> 1, wc = w & 1;
  const int mB = mt * 64 + wr * 32 + (lane >> 4) * 4;
  const int nB = nt * 64 + wc * 32 + (lane & 15);
#pragma unroll
  for (int mf = 0; mf < 2; mf++)
#pragma unroll
    for (int nf = 0; nf < 2; nf++) {
      const int n = nB + nf * 16;
      float bv = bias[n];
#pragma unroll
      for (int i = 0; i < 4; i++) {
        const int m = mB + mf * 16 + i;
        float v = fast_tanh(acc[mf][nf][i] + bv);
        size_t pi = packOff(m, n);
        sF[pi] = v;
        sB[pi] = (bf16)v;
      }
    }
}

// [pres|sa|gh] partials = s @ WP5^T, K-split x2 (grid 320)
__global__ __launch_bounds__(256) void kGemmPS(const bf16* __restrict__ Ap,
                                               const bf16* __restrict__ Bp,
                                               float* __restrict__ PS0, float* __restrict__ PS1) {
  const int t = blockIdx.x;
  const int kh = t & 1, mh = (t >> 1) & 1, nt = t >> 2;
  v4f acc[2][2] = {};
  gemmTile<16>(Ap, Bp, mh * 64, nt * 64, kh * 16, acc);
  storeTileF32(kh ? PS1 : PS0, 5120, mh * 64, nt * 64, acc);
}

// ---------------------------------------------------------------------------
// Per-step kernels (5 launches/step, ordinary stream launches — kernel
// boundaries provide the cross-workgroup ordering; no cooperative launch).
// ---------------------------------------------------------------------------

// Output phase for step `step`: pre = pres + prec + prey + bsum;
// y = softmax(tanh(pre)) -> out[:,step,:] and packed y (for next y-GEMM).
static __device__ __forceinline__ void outPhase(
    int b, int step,
    const float* __restrict__ PS0, const float* __restrict__ PS1,
    const float* __restrict__ gcp0, const float* __restrict__ gcp1,
    const float* __restrict__ ygp, const float* __restrict__ bsum,
    float* __restrict__ out, bf16* __restrict__ y_b16p, float* smred) {
  const int tid = threadIdx.x, lane = tid & 63, w = tid >> 6;
  const int v0 = tid * 4;
  const size_t o5 = (size_t)b * 5120 + v0;
  const size_t o4 = (size_t)b * 4096 + 3072 + v0;
  v4f pre = *(const v4f*)(PS0 + o5);
  pre += *(const v4f*)(PS1 + o5);
  pre += *(const v4f*)(gcp0 + o4);
  pre += *(const v4f*)(gcp1 + o4);
  pre += *(const v4f*)(ygp + o4);
  pre += *(const v4f*)(bsum + v0);
  float ee[4];
  float psum = 0.f;
#pragma unroll
  for (int i = 0; i < 4; i++) { ee[i] = __expf(fast_tanh(pre[i])); psum += ee[i]; }
#pragma unroll
  for (int off = 32; off; off >>= 1) psum += __shfl_down(psum, off, 64);
  if (lane == 0) smred[w] = psum;
  __syncthreads();
  const float rden = __builtin_amdgcn_rcpf(smred[0] + smred[1] + smred[2] + smred[3]);
  v4f y4;
#pragma unroll
  for (int i = 0; i < 4; i++) y4[i] = ee[i] * rden;
  *(v4f*)(out + ((size_t)b * 128 + step) * 1024 + v0) = y4;
  *(v4bf*)(y_b16p + packOff(b, v0)) = __builtin_convertvector(y4, v4bf);
}

// A: wg<256: attention scores for `step` (2 wgs per b, 128 t each) -> esh_g.
//    wg>=256 (128 wgs): output softmax for step-1 (skipped when step==0).
__global__ __launch_bounds__(256) void kScoresOut(
    const float* __restrict__ PS0, const float* __restrict__ PS1,
    const float* __restrict__ b_s_a, const float* __restrict__ w_a,
    const bf16* __restrict__ twb,
    const float* __restrict__ gcp0, const float* __restrict__ gcp1,
    const float* __restrict__ ygp, const float* __restrict__ bsum,
    float* __restrict__ esh_g, float* __restrict__ out,
    bf16* __restrict__ y_b16p, int step) {
  __shared__ float sm[2052];
  const int tid = threadIdx.x, lane = tid & 63, w = tid >> 6;
  if (blockIdx.x >= 256) {
    if (step == 0) return;
    outPhase(blockIdx.x - 256, step - 1, PS0, PS1, gcp0, gcp1, ygp, bsum,
             out, y_b16p, sm + 2048);
    return;
  }
  const int b = blockIdx.x >> 1, half = blockIdx.x & 1;
  float* ts = sm;
  float* wa = sm + 1024;
#pragma unroll
  for (int jj = 0; jj < 4; jj++) {
    int j = tid + jj * 256;
    float sa = PS0[(size_t)b * 5120 + 1024 + j] + PS1[(size_t)b * 5120 + 1024 + j] + b_s_a[j];
    float t = fast_tanh(sa);
    ts[j] = fminf(fmaxf(t, -0.99999994f), 0.99999994f);  // keep identity denom != 0
    wa[j] = w_a[j];
  }
  __syncthreads();
  float tj[16], wj[16];
  const int h0 = lane * 16;
#pragma unroll
  for (int j = 0; j < 16; j++) { tj[j] = ts[h0 + j]; wj[j] = wa[h0 + j]; }
  // tanh(a+b) = (tanh a + tanh b) / (1 + tanh a * tanh b), tw = tanh(wh) precomputed
  const bf16* twB = twb + ((size_t)b * 256 + half * 128 + w * 32) * 1024 + h0;
  for (int ti = 0; ti < 32; ti++) {
    const bf16* p = twB + (size_t)ti * 1024;
    v8bf t8a = *(const v8bf*)p;
    v8bf t8b = *(const v8bf*)(p + 8);
    float acc = 0.f;
#pragma unroll
    for (int j = 0; j < 8; j++) {
      float tv = (float)t8a[j];
      acc += wj[j] * (tv + tj[j]) * __builtin_amdgcn_rcpf(__builtin_fmaf(tv, tj[j], 1.f));
      float tv2 = (float)t8b[j];
      acc += wj[8 + j] * (tv2 + tj[8 + j]) * __builtin_amdgcn_rcpf(__builtin_fmaf(tv2, tj[8 + j], 1.f));
    }
#pragma unroll
    for (int off = 32; off; off >>= 1) acc += __shfl_down(acc, off, 64);
    if (lane == 0) esh_g[(size_t)b * 256 + half * 128 + w * 32 + ti] = __expf(acc);
  }
}

// B: wg<128: softmax-normalize + context c[b] -> packed bf16.
//    wg>=128 (128 tiles): ygp = y @ W2^T (M=128, N=4096).
__global__ __launch_bounds__(256) void kCtxY(
    const float* __restrict__ esh_g, const bf16* __restrict__ hb,
    const bf16* __restrict__ y_b16p, const bf16* __restrict__ W2p,
    bf16* __restrict__ c_b16p, float* __restrict__ ygp) {
  __shared__ float sm[1028];
  const int tid = threadIdx.x, lane = tid & 63, w = tid >> 6;
  if (blockIdx.x < 128) {
    const int b = blockIdx.x;
    float ev = esh_g[(size_t)b * 256 + tid];
    sm[tid] = ev;
    float p = ev;
#pragma unroll
    for (int off = 32; off; off >>= 1) p += __shfl_down(p, off, 64);
    if (lane == 0) sm[1024 + w] = p;
    __syncthreads();
    const float rden = __builtin_amdgcn_rcpf(sm[1024] + sm[1025] + sm[1026] + sm[1027]);
    const int d0 = tid * 4;
    const bf16* hp = hb + (size_t)b * 262144 + d0;
    v4f cacc = {};
#pragma unroll 8
    for (int t = 0; t < 256; t++) {
      v4bf h4 = *(const v4bf*)hp;
      hp += 1024;
      cacc += sm[t] * __builtin_convertvector(h4, v4f);
    }
    cacc *= rden;
    *(v4bf*)(c_b16p + packOff(b, d0)) = __builtin_convertvector(cacc, v4bf);
  } else {
    const int tile = blockIdx.x - 128;
    const int nt = tile & 63, mh = tile >> 6;
    v4f acc[2][2] = {};
    gemmTile<32>(y_b16p, W2p, mh * 64, nt * 64, 0, acc);
    storeTileF32(ygp, 4096, mh * 64, nt * 64, acc);
  }
}

// C: gcp partials = c @ W3^T, K-split x2 (grid 256, 1:1)
__global__ __launch_bounds__(256) void kCGemm(
    const bf16* __restrict__ c_b16p, const bf16* __restrict__ W3p,
    float* __restrict__ gcp0, float* __restrict__ gcp1) {
  const int kh = blockIdx.x & 1, mh = (blockIdx.x >> 1) & 1, nt = blockIdx.x >> 2;
  v4f acc[2][2] = {};
  gemmTile<16>(c_b16p, W3p, mh * 64, nt * 64, kh * 16, acc);
  storeTileF32(kh ? gcp1 : gcp0, 4096, mh * 64, nt * 64, acc);
}

// D: GRU pointwise -> s_new (packed f32 + bf16); grid 64 x 256 = 16384 thr
__global__ __launch_bounds__(256) void kGru(
    const float* __restrict__ gcp0, const float* __restrict__ gcp1,
    const float* __restrict__ ygp,
    const float* __restrict__ PS0, const float* __restrict__ PS1,
    const float* __restrict__ gru_b_ih, const float* __restrict__ gru_b_hh,
    float* __restrict__ s_f32p, bf16* __restrict__ s_b16p) {
  const int th = blockIdx.x * 256 + threadIdx.x;
  const int rb = th >> 11, ks = (th >> 6) & 31, l = th & 63;
  const int r = rb * 16 + (l & 15);
  const int j0 = ks * 32 + ((l >> 4) & 3) * 8;
  const float* g0 = gcp0 + (size_t)r * 4096 + j0;
  const float* g1 = gcp1 + (size_t)r * 4096 + j0;
  const float* yg = ygp + (size_t)r * 4096 + j0;
  const float* p0 = PS0 + (size_t)r * 5120 + j0;
  const float* p1 = PS1 + (size_t)r * 5120 + j0;
  const float* bih = gru_b_ih + j0;
  const float* bhh = gru_b_hh + j0;
  float sv[8], sn[8];
  *(v4f*)sv = *(const v4f*)(s_f32p + (size_t)th * 8);
  *(v4f*)(sv + 4) = *(const v4f*)(s_f32p + (size_t)th * 8 + 4);
#pragma unroll
  for (int e = 0; e < 8; e++) {
    float ir  = g0[e] + g1[e] + yg[e] + bih[e];
    float iz  = g0[1024 + e] + g1[1024 + e] + yg[1024 + e] + bih[1024 + e];
    float in_ = g0[2048 + e] + g1[2048 + e] + yg[2048 + e] + bih[2048 + e];
    float hr = p0[2048 + e] + p1[2048 + e] + bhh[e];
    float hz = p0[3072 + e] + p1[3072 + e] + bhh[1024 + e];
    float hn = p0[4096 + e] + p1[4096 + e] + bhh[2048 + e];
    float rg = fast_sigmoid(ir + hr);
    float zg = fast_sigmoid(iz + hz);
    float ng = fast_tanh(in_ + rg * hn);
    sn[e] = (1.f - zg) * ng + zg * sv[e];
  }
  *(v4f*)(s_f32p + (size_t)th * 8) = *(v4f*)sn;
  *(v4f*)(s_f32p + (size_t)th * 8 + 4) = *(v4f*)(sn + 4);
  v8bf sb;
#pragma unroll
  for (int e = 0; e < 8; e++) sb[e] = (bf16)sn[e];
  *(v8bf*)(s_b16p + (size_t)th * 8) = sb;
}

// F: final output for step 127 (grid 128)
__global__ __launch_bounds__(256) void kOutFinal(
    const float* __restrict__ PS0, const float* __restrict__ PS1,
    const float* __restrict__ gcp0, const float* __restrict__ gcp1,
    const float* __restrict__ ygp, const float* __restrict__ bsum,
    float* __restrict__ out, bf16* __restrict__ y_b16p) {
  __shared__ float smred[4];
  outPhase(blockIdx.x, 127, PS0, PS1, gcp0, gcp1, ygp, bsum, out, y_b16p, smred);
}

// ---------------------------------------------------------------------------
extern "C" void kernel_launch(void* const* d_in, const int* in_sizes, int n_in,
                              void* d_out, int out_size, void* d_ws, size_t ws_size,
                              hipStream_t stream) {
  const float* h        = (const float*)d_in[0];
  const float* w_h_a    = (const float*)d_in[1];
  const float* w_s_a    = (const float*)d_in[2];
  const float* b_s_a    = (const float*)d_in[3];
  const float* w_a      = (const float*)d_in[4];
  const float* w_init_s = (const float*)d_in[5];
  const float* b_init_s = (const float*)d_in[6];
  const float* gru_w_ih = (const float*)d_in[7];
  const float* gru_w_hh = (const float*)d_in[8];
  const float* gru_b_ih = (const float*)d_in[9];
  const float* gru_b_hh = (const float*)d_in[10];
  const float* rnn_w_ih = (const float*)d_in[11];
  const float* rnn_w_hh = (const float*)d_in[12];
  const float* rnn_b_ih = (const float*)d_in[13];
  const float* rnn_b_hh = (const float*)d_in[14];
  (void)in_sizes; (void)n_in; (void)out_size; (void)ws_size;

  char* p = (char*)d_ws;
  auto alloc = [&](size_t bytes) { char* r = p; p += (bytes + 255) & ~(size_t)255; return r; };
  bf16* hbig   = (bf16*)alloc(33554432ull * 2);   // packed h (setup), then linear bf16 h
  bf16* twb    = (bf16*)alloc(33554432ull * 2);   // tanh(h@w_h_a^T), linear
  bf16* h0p    = (bf16*)alloc(131072ull * 2);     // packed h[:,0,:]
  bf16* wbha_p = (bf16*)alloc(1048576ull * 2);
  bf16* wbini_p= (bf16*)alloc(1048576ull * 2);
  bf16* W2p    = (bf16*)alloc(4194304ull * 2);    // [gru_w_ih[:,1024:]; rnn_w_hh] packed
  bf16* W3p    = (bf16*)alloc(4194304ull * 2);    // [gru_w_ih[:,:1024]; rnn_w_ih[:,:1024]] packed
  bf16* WP5p   = (bf16*)alloc(5242880ull * 2);    // [rnn_w_ih[:,1024:]; w_s_a; gru_w_hh] packed
  float* PS0   = (float*)alloc(128ull * 5120 * 4);
  float* PS1   = (float*)alloc(128ull * 5120 * 4);
  float* gcp0  = (float*)alloc(128ull * 4096 * 4);
  float* gcp1  = (float*)alloc(128ull * 4096 * 4);
  float* ygp   = (float*)alloc(128ull * 4096 * 4);
  float* esh_g = (float*)alloc(128ull * 256 * 4);
  float* s_f32p= (float*)alloc(131072ull * 4);
  float* bsum  = (float*)alloc(1024ull * 4);
  bf16* s_b16p = (bf16*)alloc(131072ull * 2);
  bf16* y_b16p = (bf16*)alloc(131072ull * 2);
  bf16* c_b16p = (bf16*)alloc(131072ull * 2);
  float* out = (float*)d_out;

  // ---- setup: pack everything into MFMA-fragment order ----
  kPack<<<dim3(16384), 256, 0, stream>>>(h, 1024, hbig, 4194304);          // h packed (for tw GEMM)
  kPack<<<dim3(64),    256, 0, stream>>>(h, 262144, h0p, 16384);           // h[:,0,:]
  kPack<<<dim3(512),   256, 0, stream>>>(w_h_a, 1024, wbha_p, 131072);
  kPack<<<dim3(512),   256, 0, stream>>>(w_init_s, 1024, wbini_p, 131072);
  kPack<<<dim3(1536),  256, 0, stream>>>(gru_w_ih, 2048, W3p, 393216);                  // rows 0..3071
  kPack<<<dim3(512),   256, 0, stream>>>(rnn_w_ih, 2048, W3p + 3145728, 131072);        // rows 3072..4095
  kPack<<<dim3(1536),  256, 0, stream>>>(gru_w_ih + 1024, 2048, W2p, 393216);
  kPack<<<dim3(512),   256, 0, stream>>>(rnn_w_hh, 1024, W2p + 3145728, 131072);
  kPack<<<dim3(512),   256, 0, stream>>>(rnn_w_ih + 1024, 2048, WP5p, 131072);          // rows 0..1023
  kPack<<<dim3(512),   256, 0, stream>>>(w_s_a, 1024, WP5p + 1048576, 131072);          // rows 1024..2047
  kPack<<<dim3(1536),  256, 0, stream>>>(gru_w_hh, 1024, WP5p + 2097152, 393216);       // rows 2048..5119
  kPrep<<<dim3(68), 256, 0, stream>>>(rnn_b_ih, rnn_b_hh, bsum, y_b16p);

  // tw = tanh(h @ w_h_a^T) (M=32768) using packed h; then repurpose hbig as
  // LINEAR bf16 h for the context phase.
  kGemmTW<<<dim3(8192), 256, 0, stream>>>(hbig, wbha_p, twb);
  kCast4<<<dim3(32768), 256, 0, stream>>>(h, hbig, 8388608);
  // s0, then PS init = s0 @ WP5^T (K-split partials)
  kGemmS0<<<dim3(32), 256, 0, stream>>>(h0p, wbini_p, b_init_s, s_f32p, s_b16p);
  kGemmPS<<<dim3(320), 256, 0, stream>>>(s_b16p, WP5p, PS0, PS1);

  // ---- 128 sequential decode steps, 5 launches each ----
  for (int step = 0; step < 128; step++) {
    kScoresOut<<<dim3(384), 256, 0, stream>>>(PS0, PS1, b_s_a, w_a, twb,
                                              gcp0, gcp1, ygp, bsum,
                                              esh_g, out, y_b16p, step);
    kCtxY<<<dim3(256), 256, 0, stream>>>(esh_g, hbig, y_b16p, W2p, c_b16p, ygp);
    kCGemm<<<dim3(256), 256, 0, stream>>>(c_b16p, W3p, gcp0, gcp1);
    kGru<<<dim3(64), 256, 0, stream>>>(gcp0, gcp1, ygp, PS0, PS1,
                                       gru_b_ih, gru_b_hh, s_f32p, s_b16p);
    kGemmPS<<<dim3(320), 256, 0, stream>>>(s_b16p, WP5p, PS0, PS1);
  }
  kOutFinal<<<dim3(128), 256, 0, stream>>>(PS0, PS1, gcp0, gcp1, ygp, bsum, out, y_b16p);
}